// Round 12
// baseline (40530.554 us; speedup 1.0000x reference)
//
#include <hip/hip_runtime.h>
#include <float.h>

// TransitionDown: FPS -> kNN(16) -> Linear(64,128)+BN(train stats)+ReLU -> neighborhood max
#define N_PTS 32768
#define M_CL  8192
#define IN_C  64
#define OUT_C 128
#define K_NN  16
constexpr float BN_EPS_C = 1e-5f;

// ---------------- ws layout (bytes) ----------------
// 0        posx [N] f32          (prep -> knn)
// 131072   posy [N]
// 262144   posz [N]
// 393216   pts4 [N float4] sorted {x,y,z,bits(origidx)} (scatter -> fps)
//          [psum/psumsq reuse after fps]
// 917504   cellid [N] int        (prep -> scatter)
// 1048576  hist [4096] int       [scale/shift reuse after scatter]
// 1064960  start [4096] int
// 1081344  cur  [4096] int
// 1097728  ids  [M] int          (fps -> knn/sub_batch)
// 1130496  nn   [M*16] int       (knn -> pool)  ends 1654784
// 2097152  h [N*128] f32 (16 MiB) -> end 18874368

// ---------------------------------------------------------------------------
__global__ void zero_kernel(int* __restrict__ hist, int* __restrict__ cur) {
    int i = blockIdx.x * 256 + threadIdx.x;
    if (i < 4096) { hist[i] = 0; cur[i] = 0; }
}

__device__ __forceinline__ unsigned sp4(unsigned x) {
    x = (x | (x << 4)) & 0xC3u;
    x = (x | (x << 2)) & 0x249u;
    return x;
}

// 0) SoA split + Morton cell id + histogram
__global__ void prep_kernel(const float* __restrict__ pos,
                            float* __restrict__ px, float* __restrict__ py, float* __restrict__ pz,
                            int* __restrict__ cellid, int* __restrict__ hist) {
    int i = blockIdx.x * 256 + threadIdx.x;
    if (i >= N_PTS) return;
    float x = pos[3 * i + 0], y = pos[3 * i + 1], z = pos[3 * i + 2];
    px[i] = x; py[i] = y; pz[i] = z;
    int cx = (int)floorf((x + 4.0f) * 2.0f); cx = min(15, max(0, cx));
    int cy = (int)floorf((y + 4.0f) * 2.0f); cy = min(15, max(0, cy));
    int cz = (int)floorf((z + 4.0f) * 2.0f); cz = min(15, max(0, cz));
    int c = (int)(sp4((unsigned)cx) | (sp4((unsigned)cy) << 1) | (sp4((unsigned)cz) << 2));
    cellid[i] = c;
    atomicAdd(&hist[c], 1);
}

// exclusive prefix sum over 4096 bins
__global__ __launch_bounds__(1024) void scan_kernel(const int* __restrict__ hist,
                                                    int* __restrict__ start) {
    __shared__ int wtotI[16];
    const int tid = threadIdx.x;
    const int lane = tid & 63, w = tid >> 6;
    int4 hv = *reinterpret_cast<const int4*>(&hist[tid * 4]);
    int a0 = hv.x, a1 = a0 + hv.y, a2 = a1 + hv.z, a3 = a2 + hv.w;
    int tsum = a3;
    int v = tsum;
    #pragma unroll
    for (int off = 1; off < 64; off <<= 1) {
        int o = __shfl_up(v, off);
        if (lane >= off) v += o;
    }
    if (lane == 63) wtotI[w] = v;
    __syncthreads();
    if (tid < 16) {
        int v2 = wtotI[tid];
        #pragma unroll
        for (int off = 1; off < 16; off <<= 1) {
            int o = __shfl_up(v2, off);
            if (tid >= off) v2 += o;
        }
        wtotI[tid] = v2;
    }
    __syncthreads();
    int base = (w > 0 ? wtotI[w - 1] : 0) + (v - tsum);
    int4 sv;
    sv.x = base; sv.y = base + a0; sv.z = base + a1; sv.w = base + a2;
    *reinterpret_cast<int4*>(&start[tid * 4]) = sv;
}

__global__ void scatter_kernel(const float* __restrict__ px, const float* __restrict__ py,
                               const float* __restrict__ pz, const int* __restrict__ cellid,
                               const int* __restrict__ start, int* __restrict__ cur,
                               float4* __restrict__ pts4) {
    int i = blockIdx.x * 256 + threadIdx.x;
    if (i >= N_PTS) return;
    int c = cellid[i];
    int p = start[c] + atomicAdd(&cur[c], 1);
    pts4[p] = make_float4(px[i], py[i], pz[i], __uint_as_float((unsigned)i));
}

// ---------------------------------------------------------------------------
__device__ __forceinline__ unsigned long long shfl_xor_u64(unsigned long long v, int off) {
    unsigned lo = (unsigned)v, hi = (unsigned)(v >> 32);
    lo = __shfl_xor(lo, off);
    hi = __shfl_xor(hi, off);
    return ((unsigned long long)hi << 32) | (unsigned long long)lo;
}

// owner-wave region update: whole wave, one point per lane. Only the owner
// wave ever touches this region's mdL/ckeyL/cc4L -> no cross-wave hazards.
// Returns (wave-uniform) whether the region's cached key changed.
__device__ __forceinline__ bool region_update(
    int rr, float4 cc, float mm, float sx, float sy, float sz, int lane,
    float* __restrict__ mdL, unsigned long long* __restrict__ ckeyL,
    float4* __restrict__ cc4L) {
    #pragma clang fp contract(off)
    float dx = cc.x - sx;
    float dy = cc.y - sy;
    float dz = cc.z - sz;
    float xx = dx * dx, yy = dy * dy, zz = dz * dz;
    float d = (xx + yy) + zz;
    float nm = fminf(mm, d);
    bool chg = nm < mm;
    if (chg) mdL[(rr << 6) + lane] = nm;
    if (__ballot(chg)) {
        unsigned long long rk = ckeyL[rr];   // broadcast read
        float cmaxR = __uint_as_float((unsigned)(rk >> 32));
        unsigned idxR = 0x7fffffffu - (unsigned)(rk & 0xffffffffu);
        unsigned oo = __float_as_uint(cc.w);
        bool danger = chg && ((oo == idxR) || (nm == cmaxR));
        if (__ballot(danger)) {
            unsigned long long kp = ((unsigned long long)__float_as_uint(nm) << 32)
                                  | (unsigned long long)(0x7fffffffu - oo);
            unsigned long long wp = kp;
            #pragma unroll
            for (int off = 32; off; off >>= 1) {
                unsigned long long ok = shfl_xor_u64(wp, off);
                if (ok > wp) wp = ok;
            }
            if (kp == wp) {                  // unique winner lane (keys unique)
                ckeyL[rr] = wp;
                cc4L[rr] = make_float4(cc.x, cc.y, cc.z, 0.0f);
            }
            return true;
        }
    }
    return false;
}

// 1) FPS: 512 thr / 8 waves; 512 regions x 64 sorted pts; OWNER-BASED phases
//    -> ONE barrier per step. Wave w owns regions [w*64,(w+1)*64): lane k
//    prune-tests region w*64+k, wave walks its own affected-bit mask with a
//    3-deep pipelined pts4 prefetch, updates only its own regions (no queue,
//    no cross-wave LDS writes). Sole barrier: after D's partK/partC write.
//    Key u64 = (f32bits(min_d)<<32)|(0x7fffffff-origidx); u64 max ==
//    (min_d desc, idx asc) == np.argmax first-occurrence.
//    Distances bit-identical to jax f32 (unfused, (xx+yy)+zz).
__global__ __launch_bounds__(512) void fps_kernel(
    const float4* __restrict__ pts4, const float* __restrict__ pos,
    int* __restrict__ ids, float* __restrict__ out_subpos) {
    #pragma clang fp contract(off)
    __shared__ __align__(16) float mdL[N_PTS];       // 128 KiB
    __shared__ __align__(16) float4 cen4L[512];      // 8 KiB {cx,cy,cz,rad}
    __shared__ __align__(16) float4 cc4L[512];       // 8 KiB argmax coords
    __shared__ unsigned long long ckeyL[512];        // 4 KiB
    __shared__ unsigned long long partK[8];
    __shared__ __align__(16) float4 partC[8];

    const int tid = threadIdx.x;
    const int lane = tid & 63, w = tid >> 6;

    const float s0x = pos[0], s0y = pos[1], s0z = pos[2];

    // ---- init: wave w fills regions [w*64, (w+1)*64) ----
    for (int k = 0; k < 64; ++k) {
        const int r = (w << 6) + k;
        const int gi = (r << 6) + lane;
        float4 c = pts4[gi];
        float X = c.x, Y = c.y, Z = c.z;
        unsigned o = __float_as_uint(c.w);
        float mnx = X, mxx = X, mny = Y, mxy = Y, mnz = Z, mxz = Z;
        float dx = X - s0x;
        float dy = Y - s0y;
        float dz = Z - s0z;
        float xx = dx * dx, yy = dy * dy, zz = dz * dz;
        float d = (xx + yy) + zz;
        mdL[gi] = d;
        unsigned long long kp = ((unsigned long long)__float_as_uint(d) << 32)
                              | (unsigned long long)(0x7fffffffu - o);
        unsigned long long wp = kp;
        #pragma unroll
        for (int off = 32; off; off >>= 1) {
            unsigned long long ok = shfl_xor_u64(wp, off);
            if (ok > wp) wp = ok;
            mnx = fminf(mnx, __shfl_xor(mnx, off)); mxx = fmaxf(mxx, __shfl_xor(mxx, off));
            mny = fminf(mny, __shfl_xor(mny, off)); mxy = fmaxf(mxy, __shfl_xor(mxy, off));
            mnz = fminf(mnz, __shfl_xor(mnz, off)); mxz = fmaxf(mxz, __shfl_xor(mxz, off));
        }
        if (kp == wp) {  // unique winner lane writes meta
            cc4L[r] = make_float4(X, Y, Z, 0.0f);
            ckeyL[r] = wp;
        }
        // true radius: max over lanes of dist(point, center) (+ conservative slop)
        float cx = 0.5f * (mnx + mxx), cy = 0.5f * (mny + mxy), cz = 0.5f * (mnz + mxz);
        float rx = X - cx, ry = Y - cy, rz = Z - cz;
        float r2 = (rx * rx + ry * ry) + rz * rz;
        #pragma unroll
        for (int off = 32; off; off >>= 1) r2 = fmaxf(r2, __shfl_xor(r2, off));
        if (lane == 0) {
            float rd = sqrtf(r2) * 1.0005f + 1e-6f;
            cen4L[r] = make_float4(cx, cy, cz, rd);
        }
    }
    if (tid == 0) {
        ids[0] = 0;
        out_subpos[0] = s0x; out_subpos[1] = s0y; out_subpos[2] = s0z;
    }
    __syncthreads();
    // initial per-wave partial over own 64 regions (key-only butterfly)
    {
        const int rr = (w << 6) + lane;
        unsigned long long myk = ckeyL[rr];
        unsigned long long wk = myk;
        #pragma unroll
        for (int off = 32; off; off >>= 1) {
            unsigned long long ok = shfl_xor_u64(wk, off);
            if (ok > wk) wk = ok;
        }
        if (myk == wk) {
            partK[w] = wk;
            float4 wc = cc4L[rr];
            partC[w] = make_float4(wc.x, wc.y, wc.z, 0.0f);
        }
    }
    __syncthreads();

    // ---- main loop: ONE barrier per step ----
    for (int t = 1; t < M_CL; ++t) {
        // A: key-only 3-stage butterfly over 8 partials + slot ballot
        unsigned long long myk = partK[lane & 7];
        unsigned long long bk = myk;
        #pragma unroll
        for (int off = 4; off; off >>= 1) {
            unsigned long long ok = shfl_xor_u64(bk, off);
            if (ok > bk) bk = ok;
        }
        unsigned long long eqm = __ballot(myk == bk);
        int slot = ((int)__ffsll(eqm) - 1) & 7;
        float4 s4 = partC[slot];                     // broadcast read
        const float sx = s4.x, sy = s4.y, sz = s4.z;
        if (tid == 0) {
            ids[t] = (int)(0x7fffffffu - (unsigned)(bk & 0xffffffffu));
            out_subpos[3 * t + 0] = sx;
            out_subpos[3 * t + 1] = sy;
            out_subpos[3 * t + 2] = sz;
        }
        // B: lane k prune-tests own region (w<<6)+k  (own-wave meta only)
        const int myr = (w << 6) + lane;
        float4 cr = cen4L[myr];
        float ex = sx - cr.x, ey = sy - cr.y, ez = sz - cr.z;
        float dc2 = (ex * ex + ey * ey) + ez * ez;
        float lb = sqrtf(dc2) * 0.9995f - cr.w;
        float cmaxf = __uint_as_float((unsigned)(ckeyL[myr] >> 32));
        bool aff = !(lb > 0.0f && lb * lb * 0.999f >= cmaxf);
        unsigned long long m = __ballot(aff);   // bit k = region (w<<6)+k

        // C: owner wave walks its own mask; 3-deep pipelined pts4 prefetch
        bool wchg = false;
        if (m) {
            unsigned long long mm = m;
            int r0 = -1, r1 = -1, r2 = -1;
            float4 c0, c1, c2; float m0 = 0, m1 = 0, m2 = 0;
            c0 = c1 = c2 = make_float4(0, 0, 0, 0);
            r0 = (w << 6) + ((int)__ffsll(mm) - 1); mm &= mm - 1;
            c0 = pts4[(r0 << 6) + lane]; m0 = mdL[(r0 << 6) + lane];
            if (mm) {
                r1 = (w << 6) + ((int)__ffsll(mm) - 1); mm &= mm - 1;
                c1 = pts4[(r1 << 6) + lane]; m1 = mdL[(r1 << 6) + lane];
            }
            if (mm) {
                r2 = (w << 6) + ((int)__ffsll(mm) - 1); mm &= mm - 1;
                c2 = pts4[(r2 << 6) + lane]; m2 = mdL[(r2 << 6) + lane];
            }
            while (r0 >= 0) {
                wchg |= region_update(r0, c0, m0, sx, sy, sz, lane, mdL, ckeyL, cc4L);
                r0 = r1; c0 = c1; m0 = m1;
                r1 = r2; c1 = c2; m1 = m2;
                if (mm) {
                    r2 = (w << 6) + ((int)__ffsll(mm) - 1); mm &= mm - 1;
                    c2 = pts4[(r2 << 6) + lane]; m2 = mdL[(r2 << 6) + lane];
                } else {
                    r2 = -1;
                }
            }
        }

        // D: re-reduce own partial only if some own region's key changed
        if (wchg) {
            const int rr = (w << 6) + lane;
            unsigned long long myk2 = ckeyL[rr];
            unsigned long long wk = myk2;
            #pragma unroll
            for (int off = 32; off; off >>= 1) {
                unsigned long long ok = shfl_xor_u64(wk, off);
                if (ok > wk) wk = ok;
            }
            if (myk2 == wk) {     // unique winner lane
                partK[w] = wk;
                float4 wc = cc4L[rr];
                partC[w] = make_float4(wc.x, wc.y, wc.z, 0.0f);
            }
        }
        __syncthreads();  // sole barrier: partials visible for next A
    }
}

// ---------------------------------------------------------------------------
__global__ void sub_batch_kernel(const int* __restrict__ ids, const int* __restrict__ batch,
                                 float* __restrict__ sub_batch) {
    int i = blockIdx.x * 256 + threadIdx.x;
    if (i < M_CL) sub_batch[i] = (float)batch[ids[i]];
}

// ---------------------------------------------------------------------------
// 2) GEMM h = x@W + b (f32 vector ALU) + fused per-block column sum / sumsq.
__global__ __launch_bounds__(256) void gemm_stats_kernel(
    const float* __restrict__ x, const float* __restrict__ W, const float* __restrict__ bias,
    float* __restrict__ h, float* __restrict__ psum, float* __restrict__ psumsq) {
    __shared__ __align__(16) float Wl[64 * 128];
    __shared__ float xl[64 * 64];
    __shared__ float st[8 * 128 * 2];

    const int t = threadIdx.x;
    const int r0 = blockIdx.x * 64;
    #pragma unroll
    for (int u = 0; u < 32; ++u) Wl[u * 256 + t] = W[u * 256 + t];
    #pragma unroll
    for (int u = 0; u < 16; ++u) { int f = u * 256 + t; xl[f] = x[r0 * 64 + f]; }
    __syncthreads();

    const int cg = t & 31;
    const int rg = t >> 5;
    float acc[8][4];
    #pragma unroll
    for (int j = 0; j < 8; ++j)
        #pragma unroll
        for (int cc = 0; cc < 4; ++cc) acc[j][cc] = 0.0f;

    #pragma unroll 4
    for (int k = 0; k < 64; ++k) {
        float4 w4 = *reinterpret_cast<const float4*>(&Wl[k * 128 + cg * 4]);
        #pragma unroll
        for (int j = 0; j < 8; ++j) {
            float xv = xl[(rg * 8 + j) * 64 + k];
            acc[j][0] = fmaf(xv, w4.x, acc[j][0]);
            acc[j][1] = fmaf(xv, w4.y, acc[j][1]);
            acc[j][2] = fmaf(xv, w4.z, acc[j][2]);
            acc[j][3] = fmaf(xv, w4.w, acc[j][3]);
        }
    }
    float4 b4 = *reinterpret_cast<const float4*>(&bias[cg * 4]);
    float s1[4] = {0, 0, 0, 0}, s2[4] = {0, 0, 0, 0};
    #pragma unroll
    for (int j = 0; j < 8; ++j) {
        float4 hv;
        hv.x = acc[j][0] + b4.x;
        hv.y = acc[j][1] + b4.y;
        hv.z = acc[j][2] + b4.z;
        hv.w = acc[j][3] + b4.w;
        *reinterpret_cast<float4*>(&h[(r0 + rg * 8 + j) * 128 + cg * 4]) = hv;
        s1[0] += hv.x; s2[0] += hv.x * hv.x;
        s1[1] += hv.y; s2[1] += hv.y * hv.y;
        s1[2] += hv.z; s2[2] += hv.z * hv.z;
        s1[3] += hv.w; s2[3] += hv.w * hv.w;
    }
    #pragma unroll
    for (int cc = 0; cc < 4; ++cc) {
        st[(rg * 128 + cg * 4 + cc) * 2 + 0] = s1[cc];
        st[(rg * 128 + cg * 4 + cc) * 2 + 1] = s2[cc];
    }
    __syncthreads();
    if (t < 128) {
        float a = 0.0f, q = 0.0f;
        #pragma unroll
        for (int g = 0; g < 8; ++g) {
            a += st[(g * 128 + t) * 2 + 0];
            q += st[(g * 128 + t) * 2 + 1];
        }
        psum[blockIdx.x * 128 + t] = a;
        psumsq[blockIdx.x * 128 + t] = q;
    }
}

// ---------------------------------------------------------------------------
__global__ void bn_finalize_kernel(const float* __restrict__ psum, const float* __restrict__ psumsq,
                                   const float* __restrict__ gamma, const float* __restrict__ beta,
                                   float* __restrict__ scale, float* __restrict__ shift) {
    int c = threadIdx.x;
    float s = 0.0f, q = 0.0f;
    #pragma unroll 8
    for (int p = 0; p < 512; ++p) {
        s += psum[p * 128 + c];
        q += psumsq[p * 128 + c];
    }
    float mean = s * (1.0f / N_PTS);
    float var = q * (1.0f / N_PTS) - mean * mean;
    float sc = gamma[c] * rsqrtf(var + BN_EPS_C);
    scale[c] = sc;
    shift[c] = beta[c] - mean * sc;
}

// ---------------------------------------------------------------------------
// 4) kNN: one wave per query; per-lane top-16 lex (d, idx); shuffle merge.
__global__ __launch_bounds__(256) void knn_kernel(
    const float* __restrict__ posx, const float* __restrict__ posy, const float* __restrict__ posz,
    const int* __restrict__ ids, int* __restrict__ nn) {
    const int lane = threadIdx.x & 63;
    const int q = blockIdx.x * 4 + (threadIdx.x >> 6);
    const int qi = ids[q];
    const float qx = posx[qi], qy = posy[qi], qz = posz[qi];

    float dv[16]; int di[16];
    #pragma unroll
    for (int j = 0; j < 16; ++j) { dv[j] = FLT_MAX; di[j] = 0x7fffffff; }
    float wm = FLT_MAX; int wmi = 0x7fffffff; int wslot = 0;

    for (int s = 0; s < N_PTS / 64; ++s) {
        int i = s * 64 + lane;
        float dx = posx[i] - qx, dy = posy[i] - qy, dz = posz[i] - qz;
        float d = fmaf(dx, dx, fmaf(dy, dy, dz * dz));
        if (d < wm || (d == wm && i < wmi)) {
            #pragma unroll
            for (int j = 0; j < 16; ++j)
                if (j == wslot) { dv[j] = d; di[j] = i; }
            wm = -1.0f; wmi = -1;
            #pragma unroll
            for (int j = 0; j < 16; ++j) {
                bool g = (dv[j] > wm) || (dv[j] == wm && di[j] > wmi);
                if (g) { wm = dv[j]; wmi = di[j]; wslot = j; }
            }
        }
    }
    for (int rr = 0; rr < 16; ++rr) {
        float bv = FLT_MAX; int bidx = 0x7fffffff;
        #pragma unroll
        for (int j = 0; j < 16; ++j) {
            bool g = (dv[j] < bv) || (dv[j] == bv && di[j] < bidx);
            if (g) { bv = dv[j]; bidx = di[j]; }
        }
        #pragma unroll
        for (int off = 32; off; off >>= 1) {
            float ov = __shfl_xor(bv, off);
            int oi = __shfl_xor(bidx, off);
            if (ov < bv || (ov == bv && oi < bidx)) { bv = ov; bidx = oi; }
        }
        if (lane == 0) nn[q * 16 + rr] = bidx;
        #pragma unroll
        for (int j = 0; j < 16; ++j)
            if (di[j] == bidx) { dv[j] = FLT_MAX; di[j] = 0x7fffffff; }
    }
}

// ---------------------------------------------------------------------------
__global__ __launch_bounds__(256) void pool_kernel(
    const float* __restrict__ h, const int* __restrict__ nn,
    const float* __restrict__ scale, const float* __restrict__ shift,
    float* __restrict__ out) {
    const int t = threadIdx.x;
    const int c = t & 127;
    const int m = blockIdx.x * 2 + (t >> 7);
    const float sc = scale[c], sh = shift[c];
    float mx = -FLT_MAX;
    #pragma unroll
    for (int k = 0; k < 16; ++k) {
        int n = nn[m * 16 + k];
        float hv = h[n * 128 + c];
        mx = fmaxf(mx, fmaf(hv, sc, sh));
    }
    out[m * 128 + c] = fmaxf(mx, 0.0f);
}

// ---------------------------------------------------------------------------
extern "C" void kernel_launch(void* const* d_in, const int* in_sizes, int n_in,
                              void* d_out, int out_size, void* d_ws, size_t ws_size,
                              hipStream_t stream) {
    const float* x     = (const float*)d_in[0];
    const float* pos   = (const float*)d_in[1];
    const int*   batch = (const int*)d_in[2];
    const float* W     = (const float*)d_in[3];
    const float* b     = (const float*)d_in[4];
    const float* gamma = (const float*)d_in[5];
    const float* beta  = (const float*)d_in[6];
    (void)in_sizes; (void)n_in; (void)out_size; (void)ws_size;

    float* out       = (float*)d_out;
    float* sub_pos   = out + (size_t)M_CL * OUT_C;
    float* sub_batch = sub_pos + (size_t)M_CL * 3;

    char* w8 = (char*)d_ws;
    float*  posx   = (float*) (w8 + 0);
    float*  posy   = (float*) (w8 + 131072);
    float*  posz   = (float*) (w8 + 262144);
    float4* pts4   = (float4*)(w8 + 393216);   // ends 917504
    int*    cellid = (int*)   (w8 + 917504);
    int*    hist   = (int*)   (w8 + 1048576);
    int*    startb = (int*)   (w8 + 1064960);
    int*    cur    = (int*)   (w8 + 1081344);
    int*    ids    = (int*)   (w8 + 1097728);
    int*    nn     = (int*)   (w8 + 1130496);
    // dead-region reuse (stream-ordered):
    float* psum   = (float*)(w8 + 393216);   // over pts4 (dead after fps)
    float* psumsq = (float*)(w8 + 655360);
    float* scale  = (float*)(w8 + 1048576);  // over hist (dead after scatter)
    float* shift  = (float*)(w8 + 1049088);
    float* h      = (float*)(w8 + 2097152);

    zero_kernel<<<32, 256, 0, stream>>>(hist, cur);
    prep_kernel<<<128, 256, 0, stream>>>(pos, posx, posy, posz, cellid, hist);
    scan_kernel<<<1, 1024, 0, stream>>>(hist, startb);
    scatter_kernel<<<128, 256, 0, stream>>>(posx, posy, posz, cellid, startb, cur, pts4);
    fps_kernel<<<1, 512, 0, stream>>>(pts4, pos, ids, sub_pos);
    sub_batch_kernel<<<32, 256, 0, stream>>>(ids, batch, sub_batch);
    gemm_stats_kernel<<<512, 256, 0, stream>>>(x, W, b, h, psum, psumsq);
    bn_finalize_kernel<<<1, 128, 0, stream>>>(psum, psumsq, gamma, beta, scale, shift);
    knn_kernel<<<2048, 256, 0, stream>>>(posx, posy, posz, ids, nn);
    pool_kernel<<<4096, 256, 0, stream>>>(h, nn, scale, shift, out);
}

// Round 13
// 18409.186 us; speedup vs baseline: 2.2016x; 2.2016x over previous
//
#include <hip/hip_runtime.h>
#include <float.h>

// TransitionDown: FPS -> kNN(16) -> Linear(64,128)+BN(train stats)+ReLU -> neighborhood max
#define N_PTS 32768
#define M_CL  8192
#define IN_C  64
#define OUT_C 128
#define K_NN  16
constexpr float BN_EPS_C = 1e-5f;

// ---------------- ws layout (bytes) ----------------
// 0        posx [N] f32          (prep -> knn)
// 131072   posy [N]
// 262144   posz [N]
// 393216   pts4 [N float4] sorted {x,y,z,bits(origidx)} (scatter -> fps)
//          [psum/psumsq reuse after fps]
// 917504   cellid [N] int        (prep -> scatter)
// 1048576  hist [4096] int       [scale/shift reuse after scatter]
// 1064960  start [4096] int
// 1081344  cur  [4096] int
// 1097728  ids  [M] int          (fps -> knn/sub_batch)
// 1130496  nn   [M*16] int       (knn -> pool)  ends 1654784
// 2097152  h [N*128] f32 (16 MiB) -> end 18874368

// ---------------------------------------------------------------------------
__global__ void zero_kernel(int* __restrict__ hist, int* __restrict__ cur) {
    int i = blockIdx.x * 256 + threadIdx.x;
    if (i < 4096) { hist[i] = 0; cur[i] = 0; }
}

__device__ __forceinline__ unsigned sp4(unsigned x) {
    x = (x | (x << 4)) & 0xC3u;
    x = (x | (x << 2)) & 0x249u;
    return x;
}

// 0) SoA split + Morton cell id + histogram
__global__ void prep_kernel(const float* __restrict__ pos,
                            float* __restrict__ px, float* __restrict__ py, float* __restrict__ pz,
                            int* __restrict__ cellid, int* __restrict__ hist) {
    int i = blockIdx.x * 256 + threadIdx.x;
    if (i >= N_PTS) return;
    float x = pos[3 * i + 0], y = pos[3 * i + 1], z = pos[3 * i + 2];
    px[i] = x; py[i] = y; pz[i] = z;
    int cx = (int)floorf((x + 4.0f) * 2.0f); cx = min(15, max(0, cx));
    int cy = (int)floorf((y + 4.0f) * 2.0f); cy = min(15, max(0, cy));
    int cz = (int)floorf((z + 4.0f) * 2.0f); cz = min(15, max(0, cz));
    int c = (int)(sp4((unsigned)cx) | (sp4((unsigned)cy) << 1) | (sp4((unsigned)cz) << 2));
    cellid[i] = c;
    atomicAdd(&hist[c], 1);
}

// exclusive prefix sum over 4096 bins
__global__ __launch_bounds__(1024) void scan_kernel(const int* __restrict__ hist,
                                                    int* __restrict__ start) {
    __shared__ int wtotI[16];
    const int tid = threadIdx.x;
    const int lane = tid & 63, w = tid >> 6;
    int4 hv = *reinterpret_cast<const int4*>(&hist[tid * 4]);
    int a0 = hv.x, a1 = a0 + hv.y, a2 = a1 + hv.z, a3 = a2 + hv.w;
    int tsum = a3;
    int v = tsum;
    #pragma unroll
    for (int off = 1; off < 64; off <<= 1) {
        int o = __shfl_up(v, off);
        if (lane >= off) v += o;
    }
    if (lane == 63) wtotI[w] = v;
    __syncthreads();
    if (tid < 16) {
        int v2 = wtotI[tid];
        #pragma unroll
        for (int off = 1; off < 16; off <<= 1) {
            int o = __shfl_up(v2, off);
            if (tid >= off) v2 += o;
        }
        wtotI[tid] = v2;
    }
    __syncthreads();
    int base = (w > 0 ? wtotI[w - 1] : 0) + (v - tsum);
    int4 sv;
    sv.x = base; sv.y = base + a0; sv.z = base + a1; sv.w = base + a2;
    *reinterpret_cast<int4*>(&start[tid * 4]) = sv;
}

__global__ void scatter_kernel(const float* __restrict__ px, const float* __restrict__ py,
                               const float* __restrict__ pz, const int* __restrict__ cellid,
                               const int* __restrict__ start, int* __restrict__ cur,
                               float4* __restrict__ pts4) {
    int i = blockIdx.x * 256 + threadIdx.x;
    if (i >= N_PTS) return;
    int c = cellid[i];
    int p = start[c] + atomicAdd(&cur[c], 1);
    pts4[p] = make_float4(px[i], py[i], pz[i], __uint_as_float((unsigned)i));
}

// ---------------------------------------------------------------------------
__device__ __forceinline__ unsigned long long shfl_xor_u64(unsigned long long v, int off) {
    unsigned lo = (unsigned)v, hi = (unsigned)(v >> 32);
    lo = __shfl_xor(lo, off);
    hi = __shfl_xor(hi, off);
    return ((unsigned long long)hi << 32) | (unsigned long long)lo;
}

// 1) FPS: 512 thr / 8 waves; 512 regions x 64 sorted pts; shared LDS meta;
//    ballot-compacted queue (load-balance); 2-deep pipelined C prefetching
//    {queue, pts4, mdL, ckeyL}; single merged danger gate per entry.
//    Key u64 = (f32bits(min_d)<<32)|(0x7fffffff-origidx); u64 max ==
//    (min_d desc, idx asc) == np.argmax first-occurrence.
//    Distances bit-identical to jax f32 (unfused, (xx+yy)+zz).
__global__ __launch_bounds__(512) void fps_kernel(
    const float4* __restrict__ pts4, const float* __restrict__ pos,
    int* __restrict__ ids, float* __restrict__ out_subpos) {
    #pragma clang fp contract(off)
    __shared__ __align__(16) float mdL[N_PTS];       // 128 KiB
    __shared__ __align__(16) float4 cen4L[512];      // 8 KiB {cx,cy,cz,rad}
    __shared__ __align__(16) float4 cc4L[512];       // 8 KiB argmax coords
    __shared__ unsigned long long ckeyL[512];        // 4 KiB
    __shared__ unsigned long long partK[8];
    __shared__ __align__(16) float4 partC[8];
    __shared__ int queue[512];
    __shared__ int qcnt;
    __shared__ int dirty[8];

    const int tid = threadIdx.x;
    const int lane = tid & 63, w = tid >> 6;

    const float s0x = pos[0], s0y = pos[1], s0z = pos[2];

    // ---- init: wave w fills regions [w*64, (w+1)*64) ----
    for (int k = 0; k < 64; ++k) {
        const int r = (w << 6) + k;
        const int gi = (r << 6) + lane;
        float4 c = pts4[gi];
        float X = c.x, Y = c.y, Z = c.z;
        unsigned o = __float_as_uint(c.w);
        float mnx = X, mxx = X, mny = Y, mxy = Y, mnz = Z, mxz = Z;
        float dx = X - s0x;
        float dy = Y - s0y;
        float dz = Z - s0z;
        float xx = dx * dx, yy = dy * dy, zz = dz * dz;
        float d = (xx + yy) + zz;
        mdL[gi] = d;
        unsigned long long kp = ((unsigned long long)__float_as_uint(d) << 32)
                              | (unsigned long long)(0x7fffffffu - o);
        unsigned long long wp = kp;
        #pragma unroll
        for (int off = 32; off; off >>= 1) {
            unsigned long long ok = shfl_xor_u64(wp, off);
            if (ok > wp) wp = ok;
            mnx = fminf(mnx, __shfl_xor(mnx, off)); mxx = fmaxf(mxx, __shfl_xor(mxx, off));
            mny = fminf(mny, __shfl_xor(mny, off)); mxy = fmaxf(mxy, __shfl_xor(mxy, off));
            mnz = fminf(mnz, __shfl_xor(mnz, off)); mxz = fmaxf(mxz, __shfl_xor(mxz, off));
        }
        if (kp == wp) {  // unique winner lane writes meta
            cc4L[r] = make_float4(X, Y, Z, 0.0f);
            ckeyL[r] = wp;
        }
        // true radius: max over lanes of dist(point, center) (+ conservative slop)
        float cx = 0.5f * (mnx + mxx), cy = 0.5f * (mny + mxy), cz = 0.5f * (mnz + mxz);
        float rx = X - cx, ry = Y - cy, rz = Z - cz;
        float r2 = (rx * rx + ry * ry) + rz * rz;
        #pragma unroll
        for (int off = 32; off; off >>= 1) r2 = fmaxf(r2, __shfl_xor(r2, off));
        if (lane == 0) {
            float rd = sqrtf(r2) * 1.0005f + 1e-6f;
            cen4L[r] = make_float4(cx, cy, cz, rd);
        }
    }
    if (tid == 0) {
        ids[0] = 0;
        out_subpos[0] = s0x; out_subpos[1] = s0y; out_subpos[2] = s0z;
        qcnt = 0;
    }
    if (tid < 8) dirty[tid] = 0;
    __syncthreads();
    // initial per-wave partial over own 64 regions (key-only butterfly)
    {
        const int rr = (w << 6) + lane;
        unsigned long long myk = ckeyL[rr];
        unsigned long long wk = myk;
        #pragma unroll
        for (int off = 32; off; off >>= 1) {
            unsigned long long ok = shfl_xor_u64(wk, off);
            if (ok > wk) wk = ok;
        }
        if (myk == wk) {
            partK[w] = wk;
            float4 wc = cc4L[rr];
            partC[w] = make_float4(wc.x, wc.y, wc.z, 0.0f);
        }
    }
    __syncthreads();

    // ---- main loop: 3 barriers/step ----
    for (int t = 1; t < M_CL; ++t) {
        // A: key-only 3-stage butterfly over 8 partials + slot ballot
        unsigned long long myk = partK[lane & 7];
        unsigned long long bk = myk;
        #pragma unroll
        for (int off = 4; off; off >>= 1) {
            unsigned long long ok = shfl_xor_u64(bk, off);
            if (ok > bk) bk = ok;
        }
        unsigned long long eqm = __ballot(myk == bk);
        int slot = ((int)__ffsll(eqm) - 1) & 7;
        float4 s4 = partC[slot];                     // broadcast read
        const float sx = s4.x, sy = s4.y, sz = s4.z;
        if (tid == 0) {
            ids[t] = (int)(0x7fffffffu - (unsigned)(bk & 0xffffffffu));
            out_subpos[3 * t + 0] = sx;
            out_subpos[3 * t + 1] = sy;
            out_subpos[3 * t + 2] = sz;
        }
        // B: each thread prune-tests its region; ballot-compacted enqueue
        float4 cr = cen4L[tid];
        float ex = sx - cr.x, ey = sy - cr.y, ez = sz - cr.z;
        float dc2 = (ex * ex + ey * ey) + ez * ez;
        float lb = sqrtf(dc2) * 0.9995f - cr.w;
        float cmaxf = __uint_as_float((unsigned)(ckeyL[tid] >> 32));
        bool aff = !(lb > 0.0f && lb * lb * 0.999f >= cmaxf);
        unsigned long long mB = __ballot(aff);
        {
            int cnt = __popcll(mB);
            int base = 0;
            if (lane == 0 && cnt) base = atomicAdd(&qcnt, cnt);
            base = __shfl(base, 0);
            if (aff) queue[base + (int)__popcll(mB & ((1ull << lane) - 1ull))] = tid;
        }
        __syncthreads();  // bar1: queue ready

        // C: 8 waves round-robin, 2-deep prefetch of {queue, pts4, mdL, ckeyL};
        //    single merged danger gate on the critical path.
        const int qn = qcnt;
        int i = w;
        if (i < qn) {
            int rA = queue[i];
            float4 cA = pts4[(rA << 6) + lane];
            float mA = mdL[(rA << 6) + lane];
            unsigned long long kA = ckeyL[rA];       // broadcast, prefetched
            while (i < qn) {
                const int iN = i + 8;
                int rN = -1; float4 cN = cA; float mN = 0.0f;
                unsigned long long kN = 0ull;
                if (iN < qn) {
                    rN = queue[iN];
                    cN = pts4[(rN << 6) + lane];
                    mN = mdL[(rN << 6) + lane];
                    kN = ckeyL[rN];
                }
                // --- process entry (rA, cA, mA, kA) ---
                {
                    float dx = cA.x - sx;
                    float dy = cA.y - sy;
                    float dz = cA.z - sz;
                    float xx = dx * dx, yy = dy * dy, zz = dz * dz;
                    float d = (xx + yy) + zz;
                    float nm = fminf(mA, d);
                    bool chg = nm < mA;
                    if (chg) mdL[(rA << 6) + lane] = nm;
                    float cmaxR = __uint_as_float((unsigned)(kA >> 32));
                    unsigned idxR = 0x7fffffffu - (unsigned)(kA & 0xffffffffu);
                    unsigned oo = __float_as_uint(cA.w);
                    bool danger = chg && ((oo == idxR) || (nm == cmaxR));
                    if (__ballot(danger)) {
                        unsigned long long kp = ((unsigned long long)__float_as_uint(nm) << 32)
                                              | (unsigned long long)(0x7fffffffu - oo);
                        unsigned long long wp = kp;
                        #pragma unroll
                        for (int off = 32; off; off >>= 1) {
                            unsigned long long ok = shfl_xor_u64(wp, off);
                            if (ok > wp) wp = ok;
                        }
                        if (kp == wp) {              // unique winner lane
                            ckeyL[rA] = wp;
                            cc4L[rA] = make_float4(cA.x, cA.y, cA.z, 0.0f);
                            dirty[rA >> 6] = 1;
                        }
                    }
                }
                i = iN; rA = rN; cA = cN; mA = mN; kA = kN;
            }
        }
        __syncthreads();  // bar2: md/meta updates visible

        // D: only dirty groups re-reduce (single-buffered partials)
        if (tid == 0) qcnt = 0;
        if (dirty[w]) {
            const int rr = (w << 6) + lane;
            unsigned long long myk2 = ckeyL[rr];
            unsigned long long wk = myk2;
            #pragma unroll
            for (int off = 32; off; off >>= 1) {
                unsigned long long ok = shfl_xor_u64(wk, off);
                if (ok > wk) wk = ok;
            }
            if (myk2 == wk) {     // unique winner lane
                partK[w] = wk;
                float4 wc = cc4L[rr];
                partC[w] = make_float4(wc.x, wc.y, wc.z, 0.0f);
                dirty[w] = 0;
            }
        }
        __syncthreads();  // bar3: partials + qcnt ready for next step
    }
}

// ---------------------------------------------------------------------------
__global__ void sub_batch_kernel(const int* __restrict__ ids, const int* __restrict__ batch,
                                 float* __restrict__ sub_batch) {
    int i = blockIdx.x * 256 + threadIdx.x;
    if (i < M_CL) sub_batch[i] = (float)batch[ids[i]];
}

// ---------------------------------------------------------------------------
// 2) GEMM h = x@W + b (f32 vector ALU) + fused per-block column sum / sumsq.
__global__ __launch_bounds__(256) void gemm_stats_kernel(
    const float* __restrict__ x, const float* __restrict__ W, const float* __restrict__ bias,
    float* __restrict__ h, float* __restrict__ psum, float* __restrict__ psumsq) {
    __shared__ __align__(16) float Wl[64 * 128];
    __shared__ float xl[64 * 64];
    __shared__ float st[8 * 128 * 2];

    const int t = threadIdx.x;
    const int r0 = blockIdx.x * 64;
    #pragma unroll
    for (int u = 0; u < 32; ++u) Wl[u * 256 + t] = W[u * 256 + t];
    #pragma unroll
    for (int u = 0; u < 16; ++u) { int f = u * 256 + t; xl[f] = x[r0 * 64 + f]; }
    __syncthreads();

    const int cg = t & 31;
    const int rg = t >> 5;
    float acc[8][4];
    #pragma unroll
    for (int j = 0; j < 8; ++j)
        #pragma unroll
        for (int cc = 0; cc < 4; ++cc) acc[j][cc] = 0.0f;

    #pragma unroll 4
    for (int k = 0; k < 64; ++k) {
        float4 w4 = *reinterpret_cast<const float4*>(&Wl[k * 128 + cg * 4]);
        #pragma unroll
        for (int j = 0; j < 8; ++j) {
            float xv = xl[(rg * 8 + j) * 64 + k];
            acc[j][0] = fmaf(xv, w4.x, acc[j][0]);
            acc[j][1] = fmaf(xv, w4.y, acc[j][1]);
            acc[j][2] = fmaf(xv, w4.z, acc[j][2]);
            acc[j][3] = fmaf(xv, w4.w, acc[j][3]);
        }
    }
    float4 b4 = *reinterpret_cast<const float4*>(&bias[cg * 4]);
    float s1[4] = {0, 0, 0, 0}, s2[4] = {0, 0, 0, 0};
    #pragma unroll
    for (int j = 0; j < 8; ++j) {
        float4 hv;
        hv.x = acc[j][0] + b4.x;
        hv.y = acc[j][1] + b4.y;
        hv.z = acc[j][2] + b4.z;
        hv.w = acc[j][3] + b4.w;
        *reinterpret_cast<float4*>(&h[(r0 + rg * 8 + j) * 128 + cg * 4]) = hv;
        s1[0] += hv.x; s2[0] += hv.x * hv.x;
        s1[1] += hv.y; s2[1] += hv.y * hv.y;
        s1[2] += hv.z; s2[2] += hv.z * hv.z;
        s1[3] += hv.w; s2[3] += hv.w * hv.w;
    }
    #pragma unroll
    for (int cc = 0; cc < 4; ++cc) {
        st[(rg * 128 + cg * 4 + cc) * 2 + 0] = s1[cc];
        st[(rg * 128 + cg * 4 + cc) * 2 + 1] = s2[cc];
    }
    __syncthreads();
    if (t < 128) {
        float a = 0.0f, q = 0.0f;
        #pragma unroll
        for (int g = 0; g < 8; ++g) {
            a += st[(g * 128 + t) * 2 + 0];
            q += st[(g * 128 + t) * 2 + 1];
        }
        psum[blockIdx.x * 128 + t] = a;
        psumsq[blockIdx.x * 128 + t] = q;
    }
}

// ---------------------------------------------------------------------------
__global__ void bn_finalize_kernel(const float* __restrict__ psum, const float* __restrict__ psumsq,
                                   const float* __restrict__ gamma, const float* __restrict__ beta,
                                   float* __restrict__ scale, float* __restrict__ shift) {
    int c = threadIdx.x;
    float s = 0.0f, q = 0.0f;
    #pragma unroll 8
    for (int p = 0; p < 512; ++p) {
        s += psum[p * 128 + c];
        q += psumsq[p * 128 + c];
    }
    float mean = s * (1.0f / N_PTS);
    float var = q * (1.0f / N_PTS) - mean * mean;
    float sc = gamma[c] * rsqrtf(var + BN_EPS_C);
    scale[c] = sc;
    shift[c] = beta[c] - mean * sc;
}

// ---------------------------------------------------------------------------
// 4) kNN: one wave per query; per-lane top-16 lex (d, idx); shuffle merge.
__global__ __launch_bounds__(256) void knn_kernel(
    const float* __restrict__ posx, const float* __restrict__ posy, const float* __restrict__ posz,
    const int* __restrict__ ids, int* __restrict__ nn) {
    const int lane = threadIdx.x & 63;
    const int q = blockIdx.x * 4 + (threadIdx.x >> 6);
    const int qi = ids[q];
    const float qx = posx[qi], qy = posy[qi], qz = posz[qi];

    float dv[16]; int di[16];
    #pragma unroll
    for (int j = 0; j < 16; ++j) { dv[j] = FLT_MAX; di[j] = 0x7fffffff; }
    float wm = FLT_MAX; int wmi = 0x7fffffff; int wslot = 0;

    for (int s = 0; s < N_PTS / 64; ++s) {
        int i = s * 64 + lane;
        float dx = posx[i] - qx, dy = posy[i] - qy, dz = posz[i] - qz;
        float d = fmaf(dx, dx, fmaf(dy, dy, dz * dz));
        if (d < wm || (d == wm && i < wmi)) {
            #pragma unroll
            for (int j = 0; j < 16; ++j)
                if (j == wslot) { dv[j] = d; di[j] = i; }
            wm = -1.0f; wmi = -1;
            #pragma unroll
            for (int j = 0; j < 16; ++j) {
                bool g = (dv[j] > wm) || (dv[j] == wm && di[j] > wmi);
                if (g) { wm = dv[j]; wmi = di[j]; wslot = j; }
            }
        }
    }
    for (int rr = 0; rr < 16; ++rr) {
        float bv = FLT_MAX; int bidx = 0x7fffffff;
        #pragma unroll
        for (int j = 0; j < 16; ++j) {
            bool g = (dv[j] < bv) || (dv[j] == bv && di[j] < bidx);
            if (g) { bv = dv[j]; bidx = di[j]; }
        }
        #pragma unroll
        for (int off = 32; off; off >>= 1) {
            float ov = __shfl_xor(bv, off);
            int oi = __shfl_xor(bidx, off);
            if (ov < bv || (ov == bv && oi < bidx)) { bv = ov; bidx = oi; }
        }
        if (lane == 0) nn[q * 16 + rr] = bidx;
        #pragma unroll
        for (int j = 0; j < 16; ++j)
            if (di[j] == bidx) { dv[j] = FLT_MAX; di[j] = 0x7fffffff; }
    }
}

// ---------------------------------------------------------------------------
__global__ __launch_bounds__(256) void pool_kernel(
    const float* __restrict__ h, const int* __restrict__ nn,
    const float* __restrict__ scale, const float* __restrict__ shift,
    float* __restrict__ out) {
    const int t = threadIdx.x;
    const int c = t & 127;
    const int m = blockIdx.x * 2 + (t >> 7);
    const float sc = scale[c], sh = shift[c];
    float mx = -FLT_MAX;
    #pragma unroll
    for (int k = 0; k < 16; ++k) {
        int n = nn[m * 16 + k];
        float hv = h[n * 128 + c];
        mx = fmaxf(mx, fmaf(hv, sc, sh));
    }
    out[m * 128 + c] = fmaxf(mx, 0.0f);
}

// ---------------------------------------------------------------------------
extern "C" void kernel_launch(void* const* d_in, const int* in_sizes, int n_in,
                              void* d_out, int out_size, void* d_ws, size_t ws_size,
                              hipStream_t stream) {
    const float* x     = (const float*)d_in[0];
    const float* pos   = (const float*)d_in[1];
    const int*   batch = (const int*)d_in[2];
    const float* W     = (const float*)d_in[3];
    const float* b     = (const float*)d_in[4];
    const float* gamma = (const float*)d_in[5];
    const float* beta  = (const float*)d_in[6];
    (void)in_sizes; (void)n_in; (void)out_size; (void)ws_size;

    float* out       = (float*)d_out;
    float* sub_pos   = out + (size_t)M_CL * OUT_C;
    float* sub_batch = sub_pos + (size_t)M_CL * 3;

    char* w8 = (char*)d_ws;
    float*  posx   = (float*) (w8 + 0);
    float*  posy   = (float*) (w8 + 131072);
    float*  posz   = (float*) (w8 + 262144);
    float4* pts4   = (float4*)(w8 + 393216);   // ends 917504
    int*    cellid = (int*)   (w8 + 917504);
    int*    hist   = (int*)   (w8 + 1048576);
    int*    startb = (int*)   (w8 + 1064960);
    int*    cur    = (int*)   (w8 + 1081344);
    int*    ids    = (int*)   (w8 + 1097728);
    int*    nn     = (int*)   (w8 + 1130496);
    // dead-region reuse (stream-ordered):
    float* psum   = (float*)(w8 + 393216);   // over pts4 (dead after fps)
    float* psumsq = (float*)(w8 + 655360);
    float* scale  = (float*)(w8 + 1048576);  // over hist (dead after scatter)
    float* shift  = (float*)(w8 + 1049088);
    float* h      = (float*)(w8 + 2097152);

    zero_kernel<<<32, 256, 0, stream>>>(hist, cur);
    prep_kernel<<<128, 256, 0, stream>>>(pos, posx, posy, posz, cellid, hist);
    scan_kernel<<<1, 1024, 0, stream>>>(hist, startb);
    scatter_kernel<<<128, 256, 0, stream>>>(posx, posy, posz, cellid, startb, cur, pts4);
    fps_kernel<<<1, 512, 0, stream>>>(pts4, pos, ids, sub_pos);
    sub_batch_kernel<<<32, 256, 0, stream>>>(ids, batch, sub_batch);
    gemm_stats_kernel<<<512, 256, 0, stream>>>(x, W, b, h, psum, psumsq);
    bn_finalize_kernel<<<1, 128, 0, stream>>>(psum, psumsq, gamma, beta, scale, shift);
    knn_kernel<<<2048, 256, 0, stream>>>(posx, posy, posz, ids, nn);
    pool_kernel<<<4096, 256, 0, stream>>>(h, nn, scale, shift, out);
}

// Round 14
// 17123.824 us; speedup vs baseline: 2.3669x; 1.0751x over previous
//
#include <hip/hip_runtime.h>
#include <float.h>

// TransitionDown: FPS -> kNN(16) -> Linear(64,128)+BN(train stats)+ReLU -> neighborhood max
#define N_PTS 32768
#define M_CL  8192
#define IN_C  64
#define OUT_C 128
#define K_NN  16
constexpr float BN_EPS_C = 1e-5f;

// ---------------- ws layout (bytes) ----------------
// 0        posx [N] f32          (prep -> knn)
// 131072   posy [N]
// 262144   posz [N]
// 393216   pts4 [N float4] sorted {x,y,z,bits(origidx)} (scatter -> fps)
//          [psum/psumsq reuse after fps]
// 917504   cellid [N] int        (prep -> scatter)
// 1048576  hist [4096] int       [scale/shift reuse after scatter]
// 1064960  start [4096] int
// 1081344  cur  [4096] int
// 1097728  ids  [M] int          (fps -> knn/sub_batch)
// 1130496  nn   [M*16] int       (knn -> pool)  ends 1654784
// 2097152  h [N*128] f32 (16 MiB) -> end 18874368

// ---------------------------------------------------------------------------
__global__ void zero_kernel(int* __restrict__ hist, int* __restrict__ cur) {
    int i = blockIdx.x * 256 + threadIdx.x;
    if (i < 4096) { hist[i] = 0; cur[i] = 0; }
}

__device__ __forceinline__ unsigned sp4(unsigned x) {
    x = (x | (x << 4)) & 0xC3u;
    x = (x | (x << 2)) & 0x249u;
    return x;
}

// 0) SoA split + Morton cell id + histogram
__global__ void prep_kernel(const float* __restrict__ pos,
                            float* __restrict__ px, float* __restrict__ py, float* __restrict__ pz,
                            int* __restrict__ cellid, int* __restrict__ hist) {
    int i = blockIdx.x * 256 + threadIdx.x;
    if (i >= N_PTS) return;
    float x = pos[3 * i + 0], y = pos[3 * i + 1], z = pos[3 * i + 2];
    px[i] = x; py[i] = y; pz[i] = z;
    int cx = (int)floorf((x + 4.0f) * 2.0f); cx = min(15, max(0, cx));
    int cy = (int)floorf((y + 4.0f) * 2.0f); cy = min(15, max(0, cy));
    int cz = (int)floorf((z + 4.0f) * 2.0f); cz = min(15, max(0, cz));
    int c = (int)(sp4((unsigned)cx) | (sp4((unsigned)cy) << 1) | (sp4((unsigned)cz) << 2));
    cellid[i] = c;
    atomicAdd(&hist[c], 1);
}

// exclusive prefix sum over 4096 bins
__global__ __launch_bounds__(1024) void scan_kernel(const int* __restrict__ hist,
                                                    int* __restrict__ start) {
    __shared__ int wtotI[16];
    const int tid = threadIdx.x;
    const int lane = tid & 63, w = tid >> 6;
    int4 hv = *reinterpret_cast<const int4*>(&hist[tid * 4]);
    int a0 = hv.x, a1 = a0 + hv.y, a2 = a1 + hv.z, a3 = a2 + hv.w;
    int tsum = a3;
    int v = tsum;
    #pragma unroll
    for (int off = 1; off < 64; off <<= 1) {
        int o = __shfl_up(v, off);
        if (lane >= off) v += o;
    }
    if (lane == 63) wtotI[w] = v;
    __syncthreads();
    if (tid < 16) {
        int v2 = wtotI[tid];
        #pragma unroll
        for (int off = 1; off < 16; off <<= 1) {
            int o = __shfl_up(v2, off);
            if (tid >= off) v2 += o;
        }
        wtotI[tid] = v2;
    }
    __syncthreads();
    int base = (w > 0 ? wtotI[w - 1] : 0) + (v - tsum);
    int4 sv;
    sv.x = base; sv.y = base + a0; sv.z = base + a1; sv.w = base + a2;
    *reinterpret_cast<int4*>(&start[tid * 4]) = sv;
}

__global__ void scatter_kernel(const float* __restrict__ px, const float* __restrict__ py,
                               const float* __restrict__ pz, const int* __restrict__ cellid,
                               const int* __restrict__ start, int* __restrict__ cur,
                               float4* __restrict__ pts4) {
    int i = blockIdx.x * 256 + threadIdx.x;
    if (i >= N_PTS) return;
    int c = cellid[i];
    int p = start[c] + atomicAdd(&cur[c], 1);
    pts4[p] = make_float4(px[i], py[i], pz[i], __uint_as_float((unsigned)i));
}

// ---------------------------------------------------------------------------
__device__ __forceinline__ unsigned long long shfl_xor_u64(unsigned long long v, int off) {
    unsigned lo = (unsigned)v, hi = (unsigned)(v >> 32);
    lo = __shfl_xor(lo, off);
    hi = __shfl_xor(hi, off);
    return ((unsigned long long)hi << 32) | (unsigned long long)lo;
}

// 1) FPS: 1024 thr / 16 waves; 512 regions x 64 sorted pts; shared LDS meta;
//    ballot-compacted queue (load-balance, qn/16 per wave); 2-deep pipelined C
//    prefetching {queue, pts4, mdL, ckeyL}; single merged danger gate.
//    Key u64 = (f32bits(min_d)<<32)|(0x7fffffff-origidx); u64 max ==
//    (min_d desc, idx asc) == np.argmax first-occurrence.
//    Distances bit-identical to jax f32 (unfused, (xx+yy)+zz).
__global__ __launch_bounds__(1024) void fps_kernel(
    const float4* __restrict__ pts4, const float* __restrict__ pos,
    int* __restrict__ ids, float* __restrict__ out_subpos) {
    #pragma clang fp contract(off)
    __shared__ __align__(16) float mdL[N_PTS];       // 128 KiB
    __shared__ __align__(16) float4 cen4L[512];      // 8 KiB {cx,cy,cz,rad}
    __shared__ __align__(16) float4 cc4L[512];       // 8 KiB argmax coords
    __shared__ unsigned long long ckeyL[512];        // 4 KiB
    __shared__ unsigned long long partK[16];
    __shared__ __align__(16) float4 partC[16];
    __shared__ int queue[512];
    __shared__ int qcnt;
    __shared__ int dirty[16];

    const int tid = threadIdx.x;
    const int lane = tid & 63, w = tid >> 6;      // w in [0,16)

    const float s0x = pos[0], s0y = pos[1], s0z = pos[2];

    // ---- init: wave w fills regions [w*32, (w+1)*32) ----
    for (int k = 0; k < 32; ++k) {
        const int r = (w << 5) + k;
        const int gi = (r << 6) + lane;
        float4 c = pts4[gi];
        float X = c.x, Y = c.y, Z = c.z;
        unsigned o = __float_as_uint(c.w);
        float mnx = X, mxx = X, mny = Y, mxy = Y, mnz = Z, mxz = Z;
        float dx = X - s0x;
        float dy = Y - s0y;
        float dz = Z - s0z;
        float xx = dx * dx, yy = dy * dy, zz = dz * dz;
        float d = (xx + yy) + zz;
        mdL[gi] = d;
        unsigned long long kp = ((unsigned long long)__float_as_uint(d) << 32)
                              | (unsigned long long)(0x7fffffffu - o);
        unsigned long long wp = kp;
        #pragma unroll
        for (int off = 32; off; off >>= 1) {
            unsigned long long ok = shfl_xor_u64(wp, off);
            if (ok > wp) wp = ok;
            mnx = fminf(mnx, __shfl_xor(mnx, off)); mxx = fmaxf(mxx, __shfl_xor(mxx, off));
            mny = fminf(mny, __shfl_xor(mny, off)); mxy = fmaxf(mxy, __shfl_xor(mxy, off));
            mnz = fminf(mnz, __shfl_xor(mnz, off)); mxz = fmaxf(mxz, __shfl_xor(mxz, off));
        }
        if (kp == wp) {  // unique winner lane writes meta
            cc4L[r] = make_float4(X, Y, Z, 0.0f);
            ckeyL[r] = wp;
        }
        // true radius: max over lanes of dist(point, center) (+ conservative slop)
        float cx = 0.5f * (mnx + mxx), cy = 0.5f * (mny + mxy), cz = 0.5f * (mnz + mxz);
        float rx = X - cx, ry = Y - cy, rz = Z - cz;
        float r2 = (rx * rx + ry * ry) + rz * rz;
        #pragma unroll
        for (int off = 32; off; off >>= 1) r2 = fmaxf(r2, __shfl_xor(r2, off));
        if (lane == 0) {
            float rd = sqrtf(r2) * 1.0005f + 1e-6f;
            cen4L[r] = make_float4(cx, cy, cz, rd);
        }
    }
    if (tid == 0) {
        ids[0] = 0;
        out_subpos[0] = s0x; out_subpos[1] = s0y; out_subpos[2] = s0z;
        qcnt = 0;
    }
    if (tid < 16) dirty[tid] = 0;
    __syncthreads();
    // initial per-wave partial over own 32 regions (keys duplicated in halves)
    {
        const int rr = (w << 5) + (lane & 31);
        unsigned long long myk = ckeyL[rr];
        unsigned long long wk = myk;
        #pragma unroll
        for (int off = 16; off; off >>= 1) {
            unsigned long long ok = shfl_xor_u64(wk, off);
            if (ok > wk) wk = ok;
        }
        if (lane < 32 && myk == wk) {
            partK[w] = wk;
            float4 wc = cc4L[rr];
            partC[w] = make_float4(wc.x, wc.y, wc.z, 0.0f);
        }
    }
    __syncthreads();

    // ---- main loop: 3 barriers/step ----
    for (int t = 1; t < M_CL; ++t) {
        // A: key-only 4-stage butterfly over 16 partials + slot ballot
        unsigned long long myk = partK[lane & 15];
        unsigned long long bk = myk;
        #pragma unroll
        for (int off = 8; off; off >>= 1) {
            unsigned long long ok = shfl_xor_u64(bk, off);
            if (ok > bk) bk = ok;
        }
        unsigned long long eqm = __ballot(myk == bk);
        int slot = ((int)__ffsll(eqm) - 1) & 15;
        float4 s4 = partC[slot];                     // broadcast read
        const float sx = s4.x, sy = s4.y, sz = s4.z;
        if (tid == 0) {
            ids[t] = (int)(0x7fffffffu - (unsigned)(bk & 0xffffffffu));
            out_subpos[3 * t + 0] = sx;
            out_subpos[3 * t + 1] = sy;
            out_subpos[3 * t + 2] = sz;
        }
        // B: threads 0..511 prune-test one region each; compacted enqueue
        bool aff = false;
        if (tid < 512) {
            float4 cr = cen4L[tid];
            float ex = sx - cr.x, ey = sy - cr.y, ez = sz - cr.z;
            float dc2 = (ex * ex + ey * ey) + ez * ez;
            float lb = sqrtf(dc2) * 0.9995f - cr.w;
            float cmaxf = __uint_as_float((unsigned)(ckeyL[tid] >> 32));
            aff = !(lb > 0.0f && lb * lb * 0.999f >= cmaxf);
        }
        unsigned long long mB = __ballot(aff);
        if (tid < 512) {
            int cnt = __popcll(mB);
            int base = 0;
            if (lane == 0 && cnt) base = atomicAdd(&qcnt, cnt);
            base = __shfl(base, 0);
            if (aff) queue[base + (int)__popcll(mB & ((1ull << lane) - 1ull))] = tid;
        }
        __syncthreads();  // bar1: queue ready

        // C: 16 waves round-robin, 2-deep prefetch of {queue, pts4, mdL, ckeyL};
        //    single merged danger gate on the critical path.
        const int qn = qcnt;
        int i = w;
        if (i < qn) {
            int rA = queue[i];
            float4 cA = pts4[(rA << 6) + lane];
            float mA = mdL[(rA << 6) + lane];
            unsigned long long kA = ckeyL[rA];       // broadcast, prefetched
            while (i < qn) {
                const int iN = i + 16;
                int rN = -1; float4 cN = cA; float mN = 0.0f;
                unsigned long long kN = 0ull;
                if (iN < qn) {
                    rN = queue[iN];
                    cN = pts4[(rN << 6) + lane];
                    mN = mdL[(rN << 6) + lane];
                    kN = ckeyL[rN];
                }
                // --- process entry (rA, cA, mA, kA) ---
                {
                    float dx = cA.x - sx;
                    float dy = cA.y - sy;
                    float dz = cA.z - sz;
                    float xx = dx * dx, yy = dy * dy, zz = dz * dz;
                    float d = (xx + yy) + zz;
                    float nm = fminf(mA, d);
                    bool chg = nm < mA;
                    if (chg) mdL[(rA << 6) + lane] = nm;
                    float cmaxR = __uint_as_float((unsigned)(kA >> 32));
                    unsigned idxR = 0x7fffffffu - (unsigned)(kA & 0xffffffffu);
                    unsigned oo = __float_as_uint(cA.w);
                    bool danger = chg && ((oo == idxR) || (nm == cmaxR));
                    if (__ballot(danger)) {
                        unsigned long long kp = ((unsigned long long)__float_as_uint(nm) << 32)
                                              | (unsigned long long)(0x7fffffffu - oo);
                        unsigned long long wp = kp;
                        #pragma unroll
                        for (int off = 32; off; off >>= 1) {
                            unsigned long long ok = shfl_xor_u64(wp, off);
                            if (ok > wp) wp = ok;
                        }
                        if (kp == wp) {              // unique winner lane
                            ckeyL[rA] = wp;
                            cc4L[rA] = make_float4(cA.x, cA.y, cA.z, 0.0f);
                            dirty[rA >> 5] = 1;
                        }
                    }
                }
                i = iN; rA = rN; cA = cN; mA = mN; kA = kN;
            }
        }
        __syncthreads();  // bar2: md/meta updates visible

        // D: only dirty groups re-reduce their 32-region partial
        if (tid == 0) qcnt = 0;
        if (dirty[w]) {
            const int rr = (w << 5) + (lane & 31);
            unsigned long long myk2 = ckeyL[rr];
            unsigned long long wk = myk2;
            #pragma unroll
            for (int off = 16; off; off >>= 1) {
                unsigned long long ok = shfl_xor_u64(wk, off);
                if (ok > wk) wk = ok;
            }
            if (lane < 32 && myk2 == wk) {   // unique winner lane (low half)
                partK[w] = wk;
                float4 wc = cc4L[rr];
                partC[w] = make_float4(wc.x, wc.y, wc.z, 0.0f);
                dirty[w] = 0;
            }
        }
        __syncthreads();  // bar3: partials + qcnt ready for next step
    }
}

// ---------------------------------------------------------------------------
__global__ void sub_batch_kernel(const int* __restrict__ ids, const int* __restrict__ batch,
                                 float* __restrict__ sub_batch) {
    int i = blockIdx.x * 256 + threadIdx.x;
    if (i < M_CL) sub_batch[i] = (float)batch[ids[i]];
}

// ---------------------------------------------------------------------------
// 2) GEMM h = x@W + b (f32 vector ALU) + fused per-block column sum / sumsq.
__global__ __launch_bounds__(256) void gemm_stats_kernel(
    const float* __restrict__ x, const float* __restrict__ W, const float* __restrict__ bias,
    float* __restrict__ h, float* __restrict__ psum, float* __restrict__ psumsq) {
    __shared__ __align__(16) float Wl[64 * 128];
    __shared__ float xl[64 * 64];
    __shared__ float st[8 * 128 * 2];

    const int t = threadIdx.x;
    const int r0 = blockIdx.x * 64;
    #pragma unroll
    for (int u = 0; u < 32; ++u) Wl[u * 256 + t] = W[u * 256 + t];
    #pragma unroll
    for (int u = 0; u < 16; ++u) { int f = u * 256 + t; xl[f] = x[r0 * 64 + f]; }
    __syncthreads();

    const int cg = t & 31;
    const int rg = t >> 5;
    float acc[8][4];
    #pragma unroll
    for (int j = 0; j < 8; ++j)
        #pragma unroll
        for (int cc = 0; cc < 4; ++cc) acc[j][cc] = 0.0f;

    #pragma unroll 4
    for (int k = 0; k < 64; ++k) {
        float4 w4 = *reinterpret_cast<const float4*>(&Wl[k * 128 + cg * 4]);
        #pragma unroll
        for (int j = 0; j < 8; ++j) {
            float xv = xl[(rg * 8 + j) * 64 + k];
            acc[j][0] = fmaf(xv, w4.x, acc[j][0]);
            acc[j][1] = fmaf(xv, w4.y, acc[j][1]);
            acc[j][2] = fmaf(xv, w4.z, acc[j][2]);
            acc[j][3] = fmaf(xv, w4.w, acc[j][3]);
        }
    }
    float4 b4 = *reinterpret_cast<const float4*>(&bias[cg * 4]);
    float s1[4] = {0, 0, 0, 0}, s2[4] = {0, 0, 0, 0};
    #pragma unroll
    for (int j = 0; j < 8; ++j) {
        float4 hv;
        hv.x = acc[j][0] + b4.x;
        hv.y = acc[j][1] + b4.y;
        hv.z = acc[j][2] + b4.z;
        hv.w = acc[j][3] + b4.w;
        *reinterpret_cast<float4*>(&h[(r0 + rg * 8 + j) * 128 + cg * 4]) = hv;
        s1[0] += hv.x; s2[0] += hv.x * hv.x;
        s1[1] += hv.y; s2[1] += hv.y * hv.y;
        s1[2] += hv.z; s2[2] += hv.z * hv.z;
        s1[3] += hv.w; s2[3] += hv.w * hv.w;
    }
    #pragma unroll
    for (int cc = 0; cc < 4; ++cc) {
        st[(rg * 128 + cg * 4 + cc) * 2 + 0] = s1[cc];
        st[(rg * 128 + cg * 4 + cc) * 2 + 1] = s2[cc];
    }
    __syncthreads();
    if (t < 128) {
        float a = 0.0f, q = 0.0f;
        #pragma unroll
        for (int g = 0; g < 8; ++g) {
            a += st[(g * 128 + t) * 2 + 0];
            q += st[(g * 128 + t) * 2 + 1];
        }
        psum[blockIdx.x * 128 + t] = a;
        psumsq[blockIdx.x * 128 + t] = q;
    }
}

// ---------------------------------------------------------------------------
__global__ void bn_finalize_kernel(const float* __restrict__ psum, const float* __restrict__ psumsq,
                                   const float* __restrict__ gamma, const float* __restrict__ beta,
                                   float* __restrict__ scale, float* __restrict__ shift) {
    int c = threadIdx.x;
    float s = 0.0f, q = 0.0f;
    #pragma unroll 8
    for (int p = 0; p < 512; ++p) {
        s += psum[p * 128 + c];
        q += psumsq[p * 128 + c];
    }
    float mean = s * (1.0f / N_PTS);
    float var = q * (1.0f / N_PTS) - mean * mean;
    float sc = gamma[c] * rsqrtf(var + BN_EPS_C);
    scale[c] = sc;
    shift[c] = beta[c] - mean * sc;
}

// ---------------------------------------------------------------------------
// 4) kNN: one wave per query; per-lane top-16 lex (d, idx); shuffle merge.
__global__ __launch_bounds__(256) void knn_kernel(
    const float* __restrict__ posx, const float* __restrict__ posy, const float* __restrict__ posz,
    const int* __restrict__ ids, int* __restrict__ nn) {
    const int lane = threadIdx.x & 63;
    const int q = blockIdx.x * 4 + (threadIdx.x >> 6);
    const int qi = ids[q];
    const float qx = posx[qi], qy = posy[qi], qz = posz[qi];

    float dv[16]; int di[16];
    #pragma unroll
    for (int j = 0; j < 16; ++j) { dv[j] = FLT_MAX; di[j] = 0x7fffffff; }
    float wm = FLT_MAX; int wmi = 0x7fffffff; int wslot = 0;

    for (int s = 0; s < N_PTS / 64; ++s) {
        int i = s * 64 + lane;
        float dx = posx[i] - qx, dy = posy[i] - qy, dz = posz[i] - qz;
        float d = fmaf(dx, dx, fmaf(dy, dy, dz * dz));
        if (d < wm || (d == wm && i < wmi)) {
            #pragma unroll
            for (int j = 0; j < 16; ++j)
                if (j == wslot) { dv[j] = d; di[j] = i; }
            wm = -1.0f; wmi = -1;
            #pragma unroll
            for (int j = 0; j < 16; ++j) {
                bool g = (dv[j] > wm) || (dv[j] == wm && di[j] > wmi);
                if (g) { wm = dv[j]; wmi = di[j]; wslot = j; }
            }
        }
    }
    for (int rr = 0; rr < 16; ++rr) {
        float bv = FLT_MAX; int bidx = 0x7fffffff;
        #pragma unroll
        for (int j = 0; j < 16; ++j) {
            bool g = (dv[j] < bv) || (dv[j] == bv && di[j] < bidx);
            if (g) { bv = dv[j]; bidx = di[j]; }
        }
        #pragma unroll
        for (int off = 32; off; off >>= 1) {
            float ov = __shfl_xor(bv, off);
            int oi = __shfl_xor(bidx, off);
            if (ov < bv || (ov == bv && oi < bidx)) { bv = ov; bidx = oi; }
        }
        if (lane == 0) nn[q * 16 + rr] = bidx;
        #pragma unroll
        for (int j = 0; j < 16; ++j)
            if (di[j] == bidx) { dv[j] = FLT_MAX; di[j] = 0x7fffffff; }
    }
}

// ---------------------------------------------------------------------------
__global__ __launch_bounds__(256) void pool_kernel(
    const float* __restrict__ h, const int* __restrict__ nn,
    const float* __restrict__ scale, const float* __restrict__ shift,
    float* __restrict__ out) {
    const int t = threadIdx.x;
    const int c = t & 127;
    const int m = blockIdx.x * 2 + (t >> 7);
    const float sc = scale[c], sh = shift[c];
    float mx = -FLT_MAX;
    #pragma unroll
    for (int k = 0; k < 16; ++k) {
        int n = nn[m * 16 + k];
        float hv = h[n * 128 + c];
        mx = fmaxf(mx, fmaf(hv, sc, sh));
    }
    out[m * 128 + c] = fmaxf(mx, 0.0f);
}

// ---------------------------------------------------------------------------
extern "C" void kernel_launch(void* const* d_in, const int* in_sizes, int n_in,
                              void* d_out, int out_size, void* d_ws, size_t ws_size,
                              hipStream_t stream) {
    const float* x     = (const float*)d_in[0];
    const float* pos   = (const float*)d_in[1];
    const int*   batch = (const int*)d_in[2];
    const float* W     = (const float*)d_in[3];
    const float* b     = (const float*)d_in[4];
    const float* gamma = (const float*)d_in[5];
    const float* beta  = (const float*)d_in[6];
    (void)in_sizes; (void)n_in; (void)out_size; (void)ws_size;

    float* out       = (float*)d_out;
    float* sub_pos   = out + (size_t)M_CL * OUT_C;
    float* sub_batch = sub_pos + (size_t)M_CL * 3;

    char* w8 = (char*)d_ws;
    float*  posx   = (float*) (w8 + 0);
    float*  posy   = (float*) (w8 + 131072);
    float*  posz   = (float*) (w8 + 262144);
    float4* pts4   = (float4*)(w8 + 393216);   // ends 917504
    int*    cellid = (int*)   (w8 + 917504);
    int*    hist   = (int*)   (w8 + 1048576);
    int*    startb = (int*)   (w8 + 1064960);
    int*    cur    = (int*)   (w8 + 1081344);
    int*    ids    = (int*)   (w8 + 1097728);
    int*    nn     = (int*)   (w8 + 1130496);
    // dead-region reuse (stream-ordered):
    float* psum   = (float*)(w8 + 393216);   // over pts4 (dead after fps)
    float* psumsq = (float*)(w8 + 655360);
    float* scale  = (float*)(w8 + 1048576);  // over hist (dead after scatter)
    float* shift  = (float*)(w8 + 1049088);
    float* h      = (float*)(w8 + 2097152);

    zero_kernel<<<32, 256, 0, stream>>>(hist, cur);
    prep_kernel<<<128, 256, 0, stream>>>(pos, posx, posy, posz, cellid, hist);
    scan_kernel<<<1, 1024, 0, stream>>>(hist, startb);
    scatter_kernel<<<128, 256, 0, stream>>>(posx, posy, posz, cellid, startb, cur, pts4);
    fps_kernel<<<1, 1024, 0, stream>>>(pts4, pos, ids, sub_pos);
    sub_batch_kernel<<<32, 256, 0, stream>>>(ids, batch, sub_batch);
    gemm_stats_kernel<<<512, 256, 0, stream>>>(x, W, b, h, psum, psumsq);
    bn_finalize_kernel<<<1, 128, 0, stream>>>(psum, psumsq, gamma, beta, scale, shift);
    knn_kernel<<<2048, 256, 0, stream>>>(posx, posy, posz, ids, nn);
    pool_kernel<<<4096, 256, 0, stream>>>(h, nn, scale, shift, out);
}